// Round 9
// baseline (210.444 us; speedup 1.0000x reference)
//
#include <hip/hip_runtime.h>

// ---------------------------------------------------------------------------
// FISTA sparse coding (verified-primitives-only rebuild of R8's economics):
//   L = ||A||_F^2 ; M = A A^T / L (128x128 bf16) ; B = X A^T / L
//   Block = 128 threads (2 waves) owns 16 samples; wave w owns codes
//   [64w, 64w+64) (4 tiles of 16).  Per iteration each wave:
//     4x ds_read_b128 (all 128 codes, R7-verified layout/swizzle)
//     16x mfma_f32_16x16x32_bf16 (R2..R7-verified operand layouts)
//     elementwise in packed f32 (negated state), 4x 8B ds_write_b64
//   -> 12 KB LDS traffic per block-iter (vs R7's 36 KB for the same work).
//   f32 state zr/xr/Bn in registers; bf16 only in the LDS/MFMA copy of z.
//   Momentum tables precomputed; last iteration peeled (f32 store).
// ---------------------------------------------------------------------------

typedef __attribute__((ext_vector_type(8))) __bf16 bf16x8;
typedef __attribute__((ext_vector_type(4))) float f32x4;
typedef __attribute__((ext_vector_type(2))) float f32x2;
typedef __attribute__((ext_vector_type(4))) unsigned short u16x4;
typedef __attribute__((ext_vector_type(2))) unsigned int u32x2;
typedef __attribute__((ext_vector_type(4))) unsigned int u32x4;

#define NITER 80

__device__ __forceinline__ unsigned short f2bf(float f) {
  unsigned int u = __builtin_bit_cast(unsigned int, f);
  u += 0x7FFFu + ((u >> 16) & 1u);   // RNE
  return (unsigned short)(u >> 16);
}
__device__ __forceinline__ float med3(float a, float b, float c) {
  float r;
  asm("v_med3_f32 %0, %1, %2, %3" : "=v"(r) : "v"(a), "v"(b), "v"(c));
  return r;
}
__device__ __forceinline__ f32x2 pk_add(f32x2 a, f32x2 b) {
  f32x2 d;
  asm("v_pk_add_f32 %0, %1, %2" : "=v"(d) : "v"(a), "v"(b));
  return d;
}
__device__ __forceinline__ f32x2 pk_mul(f32x2 a, f32x2 b) {
  f32x2 d;
  asm("v_pk_mul_f32 %0, %1, %2" : "=v"(d) : "v"(a), "v"(b));
  return d;
}
__device__ __forceinline__ f32x2 pk_fma(f32x2 a, f32x2 b, f32x2 c) {
  f32x2 d;
  asm("v_pk_fma_f32 %0, %1, %2, %3" : "=v"(d) : "v"(a), "v"(b), "v"(c));
  return d;
}
__device__ __forceinline__ unsigned cvtpk_neg(float a, float b) {
  unsigned r;   // bf16(-a) | bf16(-b)<<16, RNE
  asm("v_cvt_pk_bf16_f32 %0, -%1, -%2" : "=v"(r) : "v"(a), "v"(b));
  return r;
}

// ---- kernel 1: A(f32) -> A_bf16, plus per-block partial sums of A^2 --------
__global__ __launch_bounds__(256) void prep_a(const float* __restrict__ A,
                                              unsigned short* __restrict__ Abf,
                                              float* __restrict__ partials) {
  int tid = threadIdx.x;
  int idx = (blockIdx.x * 256 + tid) * 4;          // 128 blocks * 1024 f32
  float4 v = *(const float4*)(A + idx);
  u16x4 o;
  o[0] = f2bf(v.x); o[1] = f2bf(v.y); o[2] = f2bf(v.z); o[3] = f2bf(v.w);
  *(u16x4*)(Abf + idx) = o;
  float p = v.x * v.x + v.y * v.y + v.z * v.z + v.w * v.w;
#pragma unroll
  for (int m = 32; m >= 1; m >>= 1) p += __shfl_xor(p, m, 64);
  __shared__ float red[4];
  if ((tid & 63) == 0) red[tid >> 6] = p;
  __syncthreads();
  if (tid == 0) partials[blockIdx.x] = red[0] + red[1] + red[2] + red[3];
}

// ---- kernel 2: M_bf16 = A A^T / L; L; momentum tables (-c_k, 1+c_k) --------
__global__ __launch_bounds__(256) void prep_m(const float* __restrict__ A,
                                              const float* __restrict__ partials,
                                              float* __restrict__ Lout,
                                              unsigned short* __restrict__ Mb,
                                              float* __restrict__ nct,
                                              float* __restrict__ cpt) {
  int tid = threadIdx.x;
  int k = blockIdx.x;
  int w = tid >> 6, l = tid & 63;
  __shared__ float ak[1024];
  *(float4*)(ak + tid * 4) = *(const float4*)(A + k * 1024 + tid * 4);
  float L = 0.f;
#pragma unroll 1
  for (int i = 0; i < 128; ++i) L += partials[i];  // fixed order: deterministic
  float invL = 1.0f / L;
  if (k == 0 && tid == 0) {
    Lout[0] = L;
    float t = 1.0f;
#pragma unroll 1
    for (int i = 0; i < NITER; ++i) {
      float tn = 0.5f * (1.0f + sqrtf(1.0f + 4.0f * t * t));
      float c = (t - 1.0f) / tn;
      nct[i] = -c;
      cpt[i] = 1.0f + c;
      t = tn;
    }
  }
  __syncthreads();
#pragma unroll 1
  for (int jj = 0; jj < 32; ++jj) {
    int j = w * 32 + jj;
    const float* aj = A + j * 1024;
    float p = 0.f;
#pragma unroll
    for (int q = 0; q < 4; ++q) {
      float4 x = *(const float4*)(aj + q * 256 + l * 4);
      float4 y = *(const float4*)(ak + q * 256 + l * 4);
      p += x.x * y.x + x.y * y.y + x.z * y.z + x.w * y.w;
    }
#pragma unroll
    for (int m = 32; m >= 1; m >>= 1) p += __shfl_xor(p, m, 64);
    if (l == 0) Mb[k * 128 + j] = f2bf(p * invL);
  }
}

// ---- kernel 3: FISTA, block = 2 waves x 16 samples; wave w: 64 codes -------
// lane l: li=l&15 (sample), g=l>>4.
//   mfr[t][m] : A-frag of M rows 64w+16t+li, k=32m+8g..+8    (t<4, m<4)
//   zf[m]     : B-frag, col(sample)=li, k(code)=32m+8g..+8   (all 128 codes)
//   d/D[t]    : codes 64w+16t+4g+r (r<4), sample li
// LDS z bf16 [buf(2)][16 samples][128 codes]; 16B chunks XOR-swizzled by
// sample: ushort = li*128 + ((chunk ^ li)*8) + within.
__global__ __launch_bounds__(128, 3) void fista(const float* __restrict__ X,
                                                const unsigned short* __restrict__ Abf,
                                                const unsigned short* __restrict__ Mb,
                                                const float* __restrict__ Lptr,
                                                const float* __restrict__ nct,
                                                const float* __restrict__ cpt,
                                                float* __restrict__ out) {
  int tid = threadIdx.x;
  int w = tid >> 6, l = tid & 63;
  int li = l & 15, g = l >> 4;
  int s0 = blockIdx.x * 16;

  __shared__ __align__(16) unsigned short zls[4096];  // 8 KB: 2 bufs x 4 KB

  float L = Lptr[0];
  float invL = 1.0f / L;
  float thr = 0.2f / L;
  float nthr = -thr;

  // ---- prologue: acc[t] = Abf rows(64w+16t+li) . X^T (K=1024) ----
  f32x4 acc[4];
#pragma unroll
  for (int t = 0; t < 4; ++t) acc[t] = f32x4{0.f, 0.f, 0.f, 0.f};
  const float* xrow = X + (size_t)(s0 + li) * 1024 + 8 * g;
  const unsigned short* arow = Abf + (size_t)(64 * w + li) * 1024 + 8 * g;
#pragma unroll 2
  for (int ks = 0; ks < 32; ++ks) {
    float4 v0 = *(const float4*)(xrow + ks * 32);
    float4 v1 = *(const float4*)(xrow + ks * 32 + 4);
    bf16x8 xf;
    xf[0] = (__bf16)v0.x; xf[1] = (__bf16)v0.y; xf[2] = (__bf16)v0.z; xf[3] = (__bf16)v0.w;
    xf[4] = (__bf16)v1.x; xf[5] = (__bf16)v1.y; xf[6] = (__bf16)v1.z; xf[7] = (__bf16)v1.w;
#pragma unroll
    for (int t = 0; t < 4; ++t) {
      bf16x8 af = *(const bf16x8*)(arow + (size_t)t * 16384 + ks * 32);
      acc[t] = __builtin_amdgcn_mfma_f32_16x16x32_bf16(af, xf, acc[t], 0, 0, 0);
    }
  }

  f32x4 Bn[4];
#pragma unroll
  for (int t = 0; t < 4; ++t) Bn[t] = -(acc[t] * invL);    // Bn = -B

  // f32 negated state (nz=-z, nx=-x), per tile as two f32x2 halves
  f32x2 nz[4][2], nx[4][2];
#pragma unroll
  for (int t = 0; t < 4; ++t) {
    nz[t][0] = f32x2{0.f, 0.f}; nz[t][1] = f32x2{0.f, 0.f};
    nx[t][0] = f32x2{0.f, 0.f}; nx[t][1] = f32x2{0.f, 0.f};
  }

  // M fragments (64 VGPRs), loaded after prologue (K=32 A-frag layout)
  bf16x8 mfr[4][4];
#pragma unroll
  for (int t = 0; t < 4; ++t)
#pragma unroll
    for (int m = 0; m < 4; ++m)
      mfr[t][m] = *(const bf16x8*)(Mb + (64 * w + 16 * t + li) * 128 + 32 * m + 8 * g);

  // zero buf0 (2048 ushorts over 128 threads = 16 each)
  *(u32x4*)(zls + tid * 16) = u32x4{0u, 0u, 0u, 0u};
  *(u32x4*)(zls + tid * 16 + 8) = u32x4{0u, 0u, 0u, 0u};
  __syncthreads();

  // LDS offsets (ushort units)
  int roff[4], woff[4];
#pragma unroll
  for (int m = 0; m < 4; ++m) roff[m] = li * 128 + (((4 * m + g) ^ li) * 8);
#pragma unroll
  for (int t = 0; t < 4; ++t)
    woff[t] = li * 128 + ((((8 * w + 2 * t) + (g >> 1)) ^ li) * 8) + (g & 1) * 4;

  // one momentum iteration: reads buf RD, writes buf WR (compile-time offs)
  auto body = [&](const int RD, const int WR, const int it) {
    float c_ = nct[it];    // -c_k
    float cp_ = cpt[it];   // 1+c_k
    f32x2 ncc = f32x2{c_, c_};
    f32x2 cpp = f32x2{cp_, cp_};

    bf16x8 zf[4];
#pragma unroll
    for (int m = 0; m < 4; ++m) zf[m] = *(const bf16x8*)(zls + RD + roff[m]);

    f32x4 D[4];
#pragma unroll
    for (int t = 0; t < 4; ++t) {
      f32x2 dlo = pk_add(f32x2{Bn[t][0], Bn[t][1]}, nz[t][0]);  // C = -B - z
      f32x2 dhi = pk_add(f32x2{Bn[t][2], Bn[t][3]}, nz[t][1]);
      f32x4 d = f32x4{dlo[0], dlo[1], dhi[0], dhi[1]};
      d = __builtin_amdgcn_mfma_f32_16x16x32_bf16(mfr[t][0], zf[0], d, 0, 0, 0);
      d = __builtin_amdgcn_mfma_f32_16x16x32_bf16(mfr[t][1], zf[1], d, 0, 0, 0);
      d = __builtin_amdgcn_mfma_f32_16x16x32_bf16(mfr[t][2], zf[2], d, 0, 0, 0);
      d = __builtin_amdgcn_mfma_f32_16x16x32_bf16(mfr[t][3], zf[3], d, 0, 0, 0);
      D[t] = d;                                  // D = zM - z - B
    }

#pragma unroll
    for (int t = 0; t < 4; ++t) {
      f32x4 d = D[t];
      float a0 = d[0] - med3(d[0], nthr, thr);   // nx = -x = d - clamp(d)
      float a1 = d[1] - med3(d[1], nthr, thr);
      float a2 = d[2] - med3(d[2], nthr, thr);
      float a3 = d[3] - med3(d[3], nthr, thr);
      f32x2 n01 = f32x2{a0, a1}, n23 = f32x2{a2, a3};
      f32x2 z01 = pk_fma(n01, cpp, pk_mul(nx[t][0], ncc));  // nz' = cp*nx - c*nxo
      f32x2 z23 = pk_fma(n23, cpp, pk_mul(nx[t][1], ncc));
      nx[t][0] = n01; nx[t][1] = n23;
      nz[t][0] = z01; nz[t][1] = z23;
      u32x2 pv = u32x2{cvtpk_neg(z01[0], z01[1]), cvtpk_neg(z23[0], z23[1])};
      *(u32x2*)(zls + WR + woff[t]) = pv;        // z (positive) bf16, 8B write
    }
    __syncthreads();
  };

#pragma unroll 1
  for (int u = 0; u < 39; ++u) {     // iters 0..77
    body(0, 2048, 2 * u);
    body(2048, 0, 2 * u + 1);
  }
  body(0, 2048, 78);                 // iter 78 -> z_79 in buf1

  // ---- final (80th) step: x in f32, store directly (reads buf1) ----
  {
    bf16x8 zf[4];
#pragma unroll
    for (int m = 0; m < 4; ++m) zf[m] = *(const bf16x8*)(zls + 2048 + roff[m]);
#pragma unroll
    for (int t = 0; t < 4; ++t) {
      f32x2 dlo = pk_add(f32x2{Bn[t][0], Bn[t][1]}, nz[t][0]);
      f32x2 dhi = pk_add(f32x2{Bn[t][2], Bn[t][3]}, nz[t][1]);
      f32x4 d = f32x4{dlo[0], dlo[1], dhi[0], dhi[1]};
      d = __builtin_amdgcn_mfma_f32_16x16x32_bf16(mfr[t][0], zf[0], d, 0, 0, 0);
      d = __builtin_amdgcn_mfma_f32_16x16x32_bf16(mfr[t][1], zf[1], d, 0, 0, 0);
      d = __builtin_amdgcn_mfma_f32_16x16x32_bf16(mfr[t][2], zf[2], d, 0, 0, 0);
      d = __builtin_amdgcn_mfma_f32_16x16x32_bf16(mfr[t][3], zf[3], d, 0, 0, 0);
      f32x4 xn;
#pragma unroll
      for (int r = 0; r < 4; ++r) {
        float dd = d[r];
        xn[r] = med3(dd, nthr, thr) - dd;        // x = soft(-dd)
      }
      *(f32x4*)(out + (size_t)(s0 + li) * 128 + 64 * w + 16 * t + 4 * g) = xn;
    }
  }
}

extern "C" void kernel_launch(void* const* d_in, const int* in_sizes, int n_in,
                              void* d_out, int out_size, void* d_ws, size_t ws_size,
                              hipStream_t stream) {
  const float* X = (const float*)d_in[0];          // 32768 x 1024 f32
  const float* A = (const float*)d_in[1];          // 128 x 1024 f32
  float* out = (float*)d_out;                      // 32768 x 128 f32

  float* partials      = (float*)d_ws;                                   // 128 f32
  float* Lout          = (float*)((char*)d_ws + 512);                    // 1 f32
  unsigned short* Abf  = (unsigned short*)((char*)d_ws + 528);           // 256 KB
  unsigned short* Mb   = (unsigned short*)((char*)d_ws + 528 + 262144);  // 32 KB
  float* nct           = (float*)((char*)d_ws + 528 + 262144 + 32768);   // 96 f32
  float* cpt           = (float*)((char*)d_ws + 528 + 262144 + 32768 + 384);

  prep_a<<<128, 256, 0, stream>>>(A, Abf, partials);
  prep_m<<<128, 256, 0, stream>>>(A, partials, Lout, Mb, nct, cpt);
  fista<<<2048, 128, 0, stream>>>(X, Abf, Mb, Lout, nct, cpt, out);
}

// Round 14
// 176.652 us; speedup vs baseline: 1.1913x; 1.1913x over previous
//
#include <hip/hip_runtime.h>

// ---------------------------------------------------------------------------
// FISTA sparse coding:
//   L = ||A||_F^2 ; M = A A^T / L (128x128 bf16) ; B = X A^T / L
//   Block = 512 threads (8 waves) owns 16 samples; wave w owns codes
//   [16w, 16w+16)  ->  per-wave state ~64 VGPR, no AGPR traffic, 7-8
//   independent wave-streams per SIMD.
//   Prologue stages the X-tile (16x1024) once in LDS as bf16 (read by all 8
//   waves as MFMA B-frags) -> X is fetched from HBM exactly once.
//   z bf16 in LDS double-buffer (reusing the stage region), 1 barrier/iter.
//   Negated f32 register state (nz=-z, nx=-x): packed VOP3P + med3 + cvt_pk.
//   Momentum coefficients precomputed in prep_m.  Last iteration peeled.
//   (Byte-verbatim resubmission of the R7 kernel that passed at 166-177 us.)
// ---------------------------------------------------------------------------

typedef __attribute__((ext_vector_type(8))) __bf16 bf16x8;
typedef __attribute__((ext_vector_type(4))) float f32x4;
typedef __attribute__((ext_vector_type(2))) float f32x2;
typedef __attribute__((ext_vector_type(4))) unsigned short u16x4;
typedef __attribute__((ext_vector_type(2))) unsigned int u32x2;
typedef __attribute__((ext_vector_type(4))) unsigned int u32x4;

#define NITER 80

__device__ __forceinline__ unsigned short f2bf(float f) {
  unsigned int u = __builtin_bit_cast(unsigned int, f);
  u += 0x7FFFu + ((u >> 16) & 1u);   // RNE
  return (unsigned short)(u >> 16);
}
__device__ __forceinline__ float med3(float a, float b, float c) {
  float r;
  asm("v_med3_f32 %0, %1, %2, %3" : "=v"(r) : "v"(a), "v"(b), "v"(c));
  return r;
}
__device__ __forceinline__ f32x2 pk_add(f32x2 a, f32x2 b) {
  f32x2 d;
  asm("v_pk_add_f32 %0, %1, %2" : "=v"(d) : "v"(a), "v"(b));
  return d;
}
__device__ __forceinline__ f32x2 pk_mul(f32x2 a, f32x2 b) {
  f32x2 d;
  asm("v_pk_mul_f32 %0, %1, %2" : "=v"(d) : "v"(a), "v"(b));
  return d;
}
__device__ __forceinline__ f32x2 pk_fma(f32x2 a, f32x2 b, f32x2 c) {
  f32x2 d;
  asm("v_pk_fma_f32 %0, %1, %2, %3" : "=v"(d) : "v"(a), "v"(b), "v"(c));
  return d;
}
__device__ __forceinline__ unsigned cvtpk(float a, float b) {
  unsigned r;   // bf16(a) | bf16(b)<<16, RNE
  asm("v_cvt_pk_bf16_f32 %0, %1, %2" : "=v"(r) : "v"(a), "v"(b));
  return r;
}
__device__ __forceinline__ unsigned cvtpk_neg(float a, float b) {
  unsigned r;   // bf16(-a) | bf16(-b)<<16, RNE
  asm("v_cvt_pk_bf16_f32 %0, -%1, -%2" : "=v"(r) : "v"(a), "v"(b));
  return r;
}

// ---- kernel 1: A(f32) -> A_bf16, plus per-block partial sums of A^2 --------
__global__ __launch_bounds__(256) void prep_a(const float* __restrict__ A,
                                              unsigned short* __restrict__ Abf,
                                              float* __restrict__ partials) {
  int tid = threadIdx.x;
  int idx = (blockIdx.x * 256 + tid) * 4;          // 128 blocks * 1024 f32
  float4 v = *(const float4*)(A + idx);
  u16x4 o;
  o[0] = f2bf(v.x); o[1] = f2bf(v.y); o[2] = f2bf(v.z); o[3] = f2bf(v.w);
  *(u16x4*)(Abf + idx) = o;
  float p = v.x * v.x + v.y * v.y + v.z * v.z + v.w * v.w;
#pragma unroll
  for (int m = 32; m >= 1; m >>= 1) p += __shfl_xor(p, m, 64);
  __shared__ float red[4];
  if ((tid & 63) == 0) red[tid >> 6] = p;
  __syncthreads();
  if (tid == 0) partials[blockIdx.x] = red[0] + red[1] + red[2] + red[3];
}

// ---- kernel 2: M_bf16 = A A^T / L; L; momentum tables (-c_k, 1+c_k) --------
__global__ __launch_bounds__(256) void prep_m(const float* __restrict__ A,
                                              const float* __restrict__ partials,
                                              float* __restrict__ Lout,
                                              unsigned short* __restrict__ Mb,
                                              float* __restrict__ nct,
                                              float* __restrict__ cpt) {
  int tid = threadIdx.x;
  int k = blockIdx.x;
  int w = tid >> 6, l = tid & 63;
  __shared__ float ak[1024];
  *(float4*)(ak + tid * 4) = *(const float4*)(A + k * 1024 + tid * 4);
  float L = 0.f;
#pragma unroll 1
  for (int i = 0; i < 128; ++i) L += partials[i];  // fixed order: deterministic
  float invL = 1.0f / L;
  if (k == 0 && tid == 0) {
    Lout[0] = L;
    float t = 1.0f;
#pragma unroll 1
    for (int i = 0; i < NITER; ++i) {
      float tn = 0.5f * (1.0f + sqrtf(1.0f + 4.0f * t * t));
      float c = (t - 1.0f) / tn;
      nct[i] = -c;
      cpt[i] = 1.0f + c;
      t = tn;
    }
  }
  __syncthreads();
#pragma unroll 1
  for (int jj = 0; jj < 32; ++jj) {
    int j = w * 32 + jj;
    const float* aj = A + j * 1024;
    float p = 0.f;
#pragma unroll
    for (int q = 0; q < 4; ++q) {
      float4 x = *(const float4*)(aj + q * 256 + l * 4);
      float4 y = *(const float4*)(ak + q * 256 + l * 4);
      p += x.x * y.x + x.y * y.y + x.z * y.z + x.w * y.w;
    }
#pragma unroll
    for (int m = 32; m >= 1; m >>= 1) p += __shfl_xor(p, m, 64);
    if (l == 0) Mb[k * 128 + j] = f2bf(p * invL);
  }
}

// ---- kernel 3: FISTA, block = 8 waves x 16 samples; wave w: 16 codes -------
// lane l: li=l&15 (sample), g=l>>4.
//   mfr[m] : A-frag of M, rows 16w+li, k=32m+8g..+8          (m<4)
//   zf[m]  : B-frag, col(sample)=li, k(code)=32m+8g..+8      (all 128 codes)
//   d      : codes 16w+4g+r (r<4), sample li
// LDS: ushort lds[16384] (32 KB).
//   Prologue: X-stage [16 rows][128 chunks of 8 bf16], chunk^=(row&7).
//   Iterations: z dbuf at [0,2048) and [2048,4096) ushorts,
//   [16 samples][16 chunks], chunk^=sample (li).
__global__ __launch_bounds__(512, 6) void fista(const float* __restrict__ X,
                                                const unsigned short* __restrict__ Abf,
                                                const unsigned short* __restrict__ Mb,
                                                const float* __restrict__ Lptr,
                                                const float* __restrict__ nct,
                                                const float* __restrict__ cpt,
                                                float* __restrict__ out) {
  int tid = threadIdx.x;
  int w = tid >> 6, l = tid & 63;
  int li = l & 15, g = l >> 4;
  int s0 = blockIdx.x * 16;

  __shared__ __align__(16) unsigned short lds[16384];  // 32 KB

  float L = Lptr[0];
  float invL = 1.0f / L;
  float thr = 0.2f / L;
  float nthr = -thr;

  // ---- stage X tile (16 x 1024 f32 -> bf16) into LDS, swizzled ----
  {
    int r = tid >> 5, t32 = tid & 31;           // row, 32 threads per row
    const float* xsrc = X + (size_t)(s0 + r) * 1024;
#pragma unroll
    for (int i = 0; i < 4; ++i) {
      int c = t32 + 32 * i;                     // chunk (8 bf16), k = 8c
      float4 v0 = *(const float4*)(xsrc + 8 * c);
      float4 v1 = *(const float4*)(xsrc + 8 * c + 4);
      u32x4 pk;
      pk[0] = cvtpk(v0.x, v0.y); pk[1] = cvtpk(v0.z, v0.w);
      pk[2] = cvtpk(v1.x, v1.y); pk[3] = cvtpk(v1.z, v1.w);
      *(u32x4*)(lds + r * 1024 + ((c ^ (r & 7)) * 8)) = pk;
    }
  }
  __syncthreads();

  // ---- prologue: acc = Abf_rows(16w+li) . X^T (K=1024), X from LDS ----
  f32x4 acc = f32x4{0.f, 0.f, 0.f, 0.f};
  const unsigned short* arow = Abf + (size_t)(16 * w + li) * 1024 + 8 * g;
  int lsw = li & 7;
#pragma unroll 8
  for (int ks = 0; ks < 32; ++ks) {
    bf16x8 xf = *(const bf16x8*)(lds + li * 1024 + (((4 * ks + g) ^ lsw) * 8));
    bf16x8 af = *(const bf16x8*)(arow + ks * 32);
    acc = __builtin_amdgcn_mfma_f32_16x16x32_bf16(af, xf, acc, 0, 0, 0);
  }
  __syncthreads();   // all X-stage reads done before z-zero overwrites

  float niv = -invL;
  f32x2 Bn0 = f32x2{acc[0] * niv, acc[1] * niv};   // Bn = -B
  f32x2 Bn1 = f32x2{acc[2] * niv, acc[3] * niv};
  f32x2 nz0 = f32x2{0.f, 0.f}, nz1 = f32x2{0.f, 0.f};
  f32x2 nx0 = f32x2{0.f, 0.f}, nx1 = f32x2{0.f, 0.f};

  // M fragments (16 VGPRs)
  bf16x8 mfr[4];
#pragma unroll
  for (int m = 0; m < 4; ++m)
    mfr[m] = *(const bf16x8*)(Mb + (16 * w + li) * 128 + 32 * m + 8 * g);

  // zero z buffer 0: 4096 ushorts over 512 threads = 8 ushorts each
  *(u32x4*)(lds + tid * 8) = u32x4{0u, 0u, 0u, 0u};
  __syncthreads();

  // LDS offsets (ushort units)
  int roff[4];
#pragma unroll
  for (int m = 0; m < 4; ++m) roff[m] = li * 128 + (((4 * m + g) ^ li) * 8);
  int woff = li * 128 + (((2 * w + (g >> 1)) ^ li) * 8) + (g & 1) * 4;

  // one momentum iteration: reads buf RD, writes buf WR (compile-time offs)
  auto body = [&](const int RD, const int WR, const int it) {
    float c_ = nct[it];    // -c_k (uniform scalar load)
    float cp_ = cpt[it];   // 1+c_k
    f32x2 ncc = f32x2{c_, c_};
    f32x2 cpp = f32x2{cp_, cp_};

    bf16x8 zf[4];
#pragma unroll
    for (int m = 0; m < 4; ++m) zf[m] = *(const bf16x8*)(lds + RD + roff[m]);

    f32x2 dlo = pk_add(Bn0, nz0);               // C = -B - z
    f32x2 dhi = pk_add(Bn1, nz1);
    f32x4 d = f32x4{dlo[0], dlo[1], dhi[0], dhi[1]};
    d = __builtin_amdgcn_mfma_f32_16x16x32_bf16(mfr[0], zf[0], d, 0, 0, 0);
    d = __builtin_amdgcn_mfma_f32_16x16x32_bf16(mfr[1], zf[1], d, 0, 0, 0);
    d = __builtin_amdgcn_mfma_f32_16x16x32_bf16(mfr[2], zf[2], d, 0, 0, 0);
    d = __builtin_amdgcn_mfma_f32_16x16x32_bf16(mfr[3], zf[3], d, 0, 0, 0);
    // D = zM - z - B  =>  zpre = -D ;  nx = -x = d - clamp(d)
    float a0 = d[0] - med3(d[0], nthr, thr);
    float a1 = d[1] - med3(d[1], nthr, thr);
    float a2 = d[2] - med3(d[2], nthr, thr);
    float a3 = d[3] - med3(d[3], nthr, thr);
    f32x2 n01 = f32x2{a0, a1}, n23 = f32x2{a2, a3};
    f32x2 z01 = pk_fma(n01, cpp, pk_mul(nx0, ncc));   // nz' = cp*nx - c*nx_old
    f32x2 z23 = pk_fma(n23, cpp, pk_mul(nx1, ncc));
    nx0 = n01; nx1 = n23;
    nz0 = z01; nz1 = z23;
    u32x2 pv = u32x2{cvtpk_neg(z01[0], z01[1]), cvtpk_neg(z23[0], z23[1])};
    *(u32x2*)(lds + WR + woff) = pv;            // z (positive) bf16
    __syncthreads();
  };

#pragma unroll 1
  for (int u = 0; u < 39; ++u) {     // iters 0..77
    body(0, 2048, 2 * u);
    body(2048, 0, 2 * u + 1);
  }
  body(0, 2048, 78);                 // iter 78 -> z_79 in buf1

  // ---- final (80th) step: x in f32, store directly (reads buf1) ----
  {
    bf16x8 zf[4];
#pragma unroll
    for (int m = 0; m < 4; ++m) zf[m] = *(const bf16x8*)(lds + 2048 + roff[m]);
    f32x2 dlo = pk_add(Bn0, nz0);
    f32x2 dhi = pk_add(Bn1, nz1);
    f32x4 d = f32x4{dlo[0], dlo[1], dhi[0], dhi[1]};
    d = __builtin_amdgcn_mfma_f32_16x16x32_bf16(mfr[0], zf[0], d, 0, 0, 0);
    d = __builtin_amdgcn_mfma_f32_16x16x32_bf16(mfr[1], zf[1], d, 0, 0, 0);
    d = __builtin_amdgcn_mfma_f32_16x16x32_bf16(mfr[2], zf[2], d, 0, 0, 0);
    d = __builtin_amdgcn_mfma_f32_16x16x32_bf16(mfr[3], zf[3], d, 0, 0, 0);
    f32x4 xn;
#pragma unroll
    for (int r = 0; r < 4; ++r) {
      float dd = d[r];
      xn[r] = med3(dd, nthr, thr) - dd;   // x = soft(-dd)
    }
    *(f32x4*)(out + (size_t)(s0 + li) * 128 + 16 * w + 4 * g) = xn;
  }
}

extern "C" void kernel_launch(void* const* d_in, const int* in_sizes, int n_in,
                              void* d_out, int out_size, void* d_ws, size_t ws_size,
                              hipStream_t stream) {
  const float* X = (const float*)d_in[0];          // 32768 x 1024 f32
  const float* A = (const float*)d_in[1];          // 128 x 1024 f32
  float* out = (float*)d_out;                      // 32768 x 128 f32

  float* partials      = (float*)d_ws;                                   // 128 f32
  float* Lout          = (float*)((char*)d_ws + 512);                    // 1 f32
  unsigned short* Abf  = (unsigned short*)((char*)d_ws + 528);           // 256 KB
  unsigned short* Mb   = (unsigned short*)((char*)d_ws + 528 + 262144);  // 32 KB
  float* nct           = (float*)((char*)d_ws + 528 + 262144 + 32768);   // 96 f32
  float* cpt           = (float*)((char*)d_ws + 528 + 262144 + 32768 + 384);

  prep_a<<<128, 256, 0, stream>>>(A, Abf, partials);
  prep_m<<<128, 256, 0, stream>>>(A, partials, Lout, Mb, nct, cpt);
  fista<<<2048, 512, 0, stream>>>(X, Abf, Mb, Lout, nct, cpt, out);
}